// Round 1
// 281.579 us; speedup vs baseline: 1.0598x; 1.0598x over previous
//
#include <hip/hip_runtime.h>
#include <stdint.h>

#define B_ 64
#define C_ 4
#define R_ 64
#define E_ 512
#define P_ 4
#define OS_ 256
#define L_ (R_*E_)        // 32768
#define K_ (L_*P_)        // 131072
#define M_ (B_*C_)        // 256

#define BM 256
#define BN 128
#define BK 64
#define Z_ 128            // split-K slices (was 256): halves partial traffic
#define KCH (K_/Z_)       // 1024
#define ITERS (KCH/BK)    // 16

typedef float  floatx4 __attribute__((ext_vector_type(4)));
typedef short  shortx8 __attribute__((ext_vector_type(8)));

// async global->LDS, 16 B per lane; LDS dest is wave-uniform base + lane*16
#define GLDS16(g, l) __builtin_amdgcn_global_load_lds(                      \
    (const __attribute__((address_space(1))) void*)(g),                     \
    (__attribute__((address_space(3))) void*)(l), 16, 0, 0)

static __device__ __forceinline__ unsigned short f2bf(float f) {
  union { float f; unsigned int u; } v; v.f = f;
  unsigned int u = v.u;
  u += 0x7fffu + ((u >> 16) & 1u);   // RNE
  return (unsigned short)(u >> 16);
}

// build_A v2: one thread owns 8 consecutive e -> all pool windows (k<=8) are
// thread-local (zero shuffles), all stores are 16B shortx8 (was 4x 2B).
// Block = (bc, group of 8 r): stage 8 x-rows (16KB LDS), gather, pool, store.
__global__ __launch_bounds__(512) void build_A(
    const float* __restrict__ x, const int* __restrict__ rxd_perm,
    const int* __restrict__ e_idx, const float* __restrict__ signs,
    unsigned short* __restrict__ A) {
  const int blk = blockIdx.x;         // 2048 = 256 bc * 8 rgroups
  const int bc  = blk >> 3;
  const int rg  = blk & 7;
  const int t   = threadIdx.x;
  __shared__ float xr[8][E_];         // 16 KB

  #pragma unroll
  for (int i = 0; i < 2; ++i) {       // 1024 float4 granules, 2 per thread
    const int q   = i * 512 + t;
    const int row = q >> 7;           // 0..7
    const int c4  = q & 127;
    const float4 v = *(const float4*)(
        x + ((size_t)(bc * R_ + rxd_perm[rg * 8 + row])) * E_ + c4 * 4);
    *(float4*)(&xr[row][c4 * 4]) = v;
  }
  __syncthreads();

  const int rloc = t >> 6;            // 0..7
  const int e0   = (t & 63) * 8;      // 8 consecutive e per thread
  const int r    = rg * 8 + rloc;
  const float* xp = xr[rloc];

  float v[4][8];
  #pragma unroll
  for (int i = 0; i < 8; ++i) {
    const uint4  ei = *(const uint4*)(e_idx + (size_t)(e0 + i) * 4);
    const float4 sg = *(const float4*)(signs + (size_t)(e0 + i) * 4);
    v[0][i] = xp[ei.x] * sg.x;
    v[1][i] = xp[ei.y] * sg.y;
    v[2][i] = xp[ei.z] * sg.z;
    v[3][i] = xp[ei.w] * sg.w;
  }

  unsigned short* dst = A + (size_t)bc * K_ + (size_t)r * E_ + e0;
  shortx8 o;

  // p=0: passthrough
  #pragma unroll
  for (int i = 0; i < 8; ++i) o[i] = (short)f2bf(v[0][i]);
  *(shortx8*)(dst) = o;

  // p=1: k=2 windows, first-max wins (matches argmax-first)
  #pragma unroll
  for (int j = 0; j < 4; ++j) {
    const float a = v[1][2 * j], b = v[1][2 * j + 1];
    const bool first = (a >= b);
    o[2 * j]     = (short)f2bf(first ? a : 0.0f);
    o[2 * j + 1] = (short)f2bf(first ? 0.0f : b);
  }
  *(shortx8*)(dst + L_) = o;

  // p=2: k=4 windows
  #pragma unroll
  for (int j = 0; j < 2; ++j) {
    int am = 0; float m = v[2][4 * j];
    #pragma unroll
    for (int i = 1; i < 4; ++i)
      if (v[2][4 * j + i] > m) { m = v[2][4 * j + i]; am = i; }
    #pragma unroll
    for (int i = 0; i < 4; ++i) o[4 * j + i] = (short)f2bf(i == am ? m : 0.0f);
  }
  *(shortx8*)(dst + 2 * L_) = o;

  // p=3: k=8 window
  {
    int am = 0; float m = v[3][0];
    #pragma unroll
    for (int i = 1; i < 8; ++i)
      if (v[3][i] > m) { m = v[3][i]; am = i; }
    #pragma unroll
    for (int i = 0; i < 8; ++i) o[i] = (short)f2bf(i == am ? m : 0.0f);
  }
  *(shortx8*)(dst + 3 * L_) = o;
}

// Split-K GEMM, T3-minimum pipeline: double-buffered As+Ws (96KB LDS),
// prefetch tile t+1 (W->regs issued first, then GLDS A) BEFORE compute(t),
// convert+ds_write W after compute, ONE __syncthreads per iter (its implicit
// vmcnt(0)/lgkmcnt(0) is the pipeline fence). Epilogue: plain f32 partial
// stores (no atomics); reduce_out sums Z_ partials + bias.
__global__ __launch_bounds__(512, 2) void gemm_splitk(
    const unsigned short* __restrict__ A, const float* __restrict__ W,
    float* __restrict__ Pp) {
  __shared__ unsigned short As[2][BM * BK];   // 2 x 32 KB
  __shared__ unsigned short Ws[2][BN * BK];   // 2 x 16 KB
  const int t    = threadIdx.x;
  const int lane = t & 63;
  const int wv   = t >> 6;                    // 0..7

  // id -> (z, ny): ids i and i+8 share z -> same XCD (round-robin heuristic)
  const int id = blockIdx.x;                  // 0..255
  const int ny = (id >> 3) & 1;
  const int z  = (id & 7) | ((id >> 4) << 3); // 0..127
  const int nBase = ny * BN;
  const size_t k0base = (size_t)z * KCH;

  const int wm   = (wv >> 1) * 64;
  const int wn   = (wv & 1) * 64;
  const int lrow = lane & 15;
  const int quad = lane >> 4;
  const int rx   = lrow & 7;
  const int aCh  = (lane & 7) ^ ((lane >> 3) & 7);

  // W staging geometry: 2 row-passes per thread, same granule column both
  const int wrow0 = t >> 3;                   // 0..63
  const int wch   = t & 7;
  const float* wbase0 = W + (size_t)(nBase + wrow0) * K_ + wch * 8;
  const float* wbase1 = wbase0 + (size_t)64 * K_;
  const int wslot0 = (wrow0 * 8 + (wch ^ (wrow0 & 7))) * 8;
  const int wslot1 = wslot0 + 64 * 8 * 8;     // row+64: same (row&7)

  floatx4 acc[4][4];
  #pragma unroll
  for (int i = 0; i < 4; ++i)
    #pragma unroll
    for (int j = 0; j < 4; ++j) acc[i][j] = {0.f, 0.f, 0.f, 0.f};

  float4 wr0, wr1, wr2, wr3;

  auto loadW = [&](size_t k0) {               // issue FIRST (oldest vmem)
    wr0 = *(const float4*)(wbase0 + k0);
    wr1 = *(const float4*)(wbase0 + k0 + 4);
    wr2 = *(const float4*)(wbase1 + k0);
    wr3 = *(const float4*)(wbase1 + k0 + 4);
  };
  auto stageA = [&](int buf, size_t k0) {     // 4 GLDS per wave (youngest)
    #pragma unroll
    for (int c = 0; c < 4; ++c) {
      const int sblk = (wv * 4 + c) * 64;
      const int row  = (sblk >> 3) + (lane >> 3);
      GLDS16(A + (size_t)row * K_ + k0 + (size_t)aCh * 8, &As[buf][sblk * 8]);
    }
  };
  auto writeW = [&](int buf) {                // uses wr* -> vmcnt(4) wait only
    shortx8 b0, b1;
    b0[0] = (short)f2bf(wr0.x); b0[1] = (short)f2bf(wr0.y);
    b0[2] = (short)f2bf(wr0.z); b0[3] = (short)f2bf(wr0.w);
    b0[4] = (short)f2bf(wr1.x); b0[5] = (short)f2bf(wr1.y);
    b0[6] = (short)f2bf(wr1.z); b0[7] = (short)f2bf(wr1.w);
    b1[0] = (short)f2bf(wr2.x); b1[1] = (short)f2bf(wr2.y);
    b1[2] = (short)f2bf(wr2.z); b1[3] = (short)f2bf(wr2.w);
    b1[4] = (short)f2bf(wr3.x); b1[5] = (short)f2bf(wr3.y);
    b1[6] = (short)f2bf(wr3.z); b1[7] = (short)f2bf(wr3.w);
    *(shortx8*)(&Ws[buf][wslot0]) = b0;
    *(shortx8*)(&Ws[buf][wslot1]) = b1;
  };
  auto compute = [&](int buf) {
    #pragma unroll
    for (int kh = 0; kh < 2; ++kh) {
      const int ch = kh * 4 + quad;
      shortx8 af[4], wf[4];
      #pragma unroll
      for (int ti = 0; ti < 4; ++ti) {
        const int row = wm + ti * 16 + lrow;
        af[ti] = *(const shortx8*)(&As[buf][(row * 8 + (ch ^ rx)) * 8]);
      }
      #pragma unroll
      for (int tj = 0; tj < 4; ++tj) {
        const int row = wn + tj * 16 + lrow;
        wf[tj] = *(const shortx8*)(&Ws[buf][(row * 8 + (ch ^ rx)) * 8]);
      }
      #pragma unroll
      for (int ti = 0; ti < 4; ++ti)
        #pragma unroll
        for (int tj = 0; tj < 4; ++tj)
          acc[ti][tj] = __builtin_amdgcn_mfma_f32_16x16x32_bf16(
              af[ti], wf[tj], acc[ti][tj], 0, 0, 0);
    }
  };

  // prologue: fill buffer 0
  loadW(k0base);
  stageA(0, k0base);
  writeW(0);
  __syncthreads();

  #pragma unroll 2
  for (int it = 0; it < ITERS; ++it) {
    const int b = it & 1;
    const bool pf = (it + 1 < ITERS);
    if (pf) {
      const size_t k0n = k0base + (size_t)(it + 1) * BK;
      loadW(k0n);          // 4 global f32x4 -> regs (oldest)
      stageA(b ^ 1, k0n);  // 4 GLDS -> other buffer (stay in flight)
    }
    compute(b);            // hides the prefetch latency
    if (pf) writeW(b ^ 1); // vmcnt waits W regs only; GLDS still flying
    __syncthreads();       // drains vmcnt(0)+lgkmcnt(0): buffer b^1 ready
  }

  // epilogue: plain stores of the split-K partial (no atomics)
  float* Pz = Pp + (size_t)z * (M_ * OS_);
  #pragma unroll
  for (int ti = 0; ti < 4; ++ti)
    #pragma unroll
    for (int tj = 0; tj < 4; ++tj)
      #pragma unroll
      for (int j = 0; j < 4; ++j) {
        const int m = wm + ti * 16 + quad * 4 + j;
        const int n = nBase + wn + tj * 16 + lrow;
        Pz[(size_t)m * OS_ + n] = acc[ti][tj][j];
      }
}

// out[m,n] = bias[n] + sum_z P[z,m,n] ; 16384 float4 threads, streaming 33.5MB
__global__ __launch_bounds__(64) void reduce_out(
    const float* __restrict__ Pp, const float* __restrict__ bias,
    float* __restrict__ out) {
  const int i4 = blockIdx.x * 64 + threadIdx.x;    // 0..16383
  const float* p = Pp + (size_t)i4 * 4;
  float4 s = {0.f, 0.f, 0.f, 0.f};
  #pragma unroll 8
  for (int zz = 0; zz < Z_; ++zz) {
    const float4 v = *(const float4*)(p + (size_t)zz * (M_ * OS_));
    s.x += v.x; s.y += v.y; s.z += v.z; s.w += v.w;
  }
  const float4 bb = *(const float4*)(bias + ((i4 * 4) & (OS_ - 1)));
  float4 o = {s.x + bb.x, s.y + bb.y, s.z + bb.z, s.w + bb.w};
  *(float4*)(out + (size_t)i4 * 4) = o;
}

extern "C" void kernel_launch(void* const* d_in, const int* in_sizes, int n_in,
                              void* d_out, int out_size, void* d_ws, size_t ws_size,
                              hipStream_t stream) {
  const float* x        = (const float*)d_in[0];
  const int*   rxd_perm = (const int*)d_in[1];
  const int*   e_idx    = (const int*)d_in[2];
  const float* signs    = (const float*)d_in[3];
  const float* W        = (const float*)d_in[4];
  const float* bias     = (const float*)d_in[5];
  float* out = (float*)d_out;

  unsigned short* A = (unsigned short*)d_ws;                 // 67.1 MB
  float* Pp = (float*)((char*)d_ws + (size_t)M_ * K_ * 2);   // 33.5 MB partials

  build_A<<<dim3(M_ * 8), dim3(512), 0, stream>>>(x, rxd_perm, e_idx, signs, A);
  gemm_splitk<<<dim3(2 * Z_), dim3(512), 0, stream>>>(A, W, Pp);
  reduce_out<<<dim3((M_ * OS_ / 4) / 64), dim3(64), 0, stream>>>(Pp, bias, out);
}